// Round 9
// baseline (79.860 us; speedup 1.0000x reference)
//
#include <hip/hip_runtime.h>
#include <hip/hip_bf16.h>

#define IN_DIM 512
#define OUT_DIM 512
#define BATCH 4096
#define NCTRL 17
// K reordered c-major within 64-i blocks: k = iblk*576 + c*64 + il
// c in [0,8): spline basis c; c==8: silu/w_b slot.  KDIM = 8*576 = 4608.
#define KDIM 4608
#define TM 128                // batch rows per block
#define TN 128                // out cols per block
#define BK 64
#define SPLITK 8              // one iblk (64 i's x 9 c) per block
#define KSLICE 576
#define NT 9                  // K-steps per block == c index
#define BUF_ELEMS ((TM + TN) * BK)   // 16384 elems = 32 KB
#define OUT_ELEMS ((size_t)BATCH * OUT_DIM)   // 2M

typedef unsigned short ushort_t;
typedef __attribute__((ext_vector_type(8))) short short8;
typedef __attribute__((ext_vector_type(4))) float f32x4;

__device__ inline ushort_t to_bf16(float f) {
    union { float f; unsigned int i; } v; v.f = f;
    unsigned int r = v.i + 0x7FFF + ((v.i >> 16) & 1);   // round-to-nearest-even
    return (ushort_t)(r >> 16);
}

__device__ inline float bf16_to_f(ushort_t u) {
    union { unsigned int i; float f; } v; v.i = ((unsigned int)u) << 16;
    return v.f;
}

__device__ inline void gld16(const ushort_t* g, void* l) {
    __builtin_amdgcn_global_load_lds(
        (const __attribute__((address_space(1))) void*)g,
        (__attribute__((address_space(3))) void*)l, 16, 0, 0);
}

// LDS tiles swizzled: element (row R, col k) at col k ^ ((R&7)<<3) (16B-chunk
// permutation within 128B rows). A'-side: pre-swizzled in global within each
// 64-k window -> linear gld16 staging unaffected. B-side: ds_write applies
// the XOR directly. ds_read_b128 conflict-free (verified 0 in R2..R8).

// prep_A: one block per o-row. A'[o][iblk*576 + c*64 + (il^swz)] =
// w_s*ctrl[c] (c<8) at c*64, w_b at 512.  swz = (o&7)<<3.
__global__ __launch_bounds__(512) void prep_A(const float* __restrict__ w_b,
                                              const float* __restrict__ w_s,
                                              const float* __restrict__ ctrl,
                                              ushort_t* __restrict__ A) {
    __shared__ ushort_t rowbuf[KDIM];
    int o = blockIdx.x;
    int i = threadIdx.x;
    float ws = w_s[(size_t)i * OUT_DIM + o];
    float wb = w_b[(size_t)i * OUT_DIM + o];
    const float* cp = ctrl + ((size_t)i * OUT_DIM + o) * NCTRL;
    int swz = (o & 7) << 3;
    int win0 = (i >> 6) * 576;
    int ils = (i & 63) ^ swz;
#pragma unroll
    for (int c = 0; c < 8; c++) rowbuf[win0 + c * 64 + ils] = to_bf16(ws * cp[c]);
    rowbuf[win0 + 512 + ils] = to_bf16(wb);
    __syncthreads();
    const uint4* s = (const uint4*)rowbuf;               // 576 x 16B chunks
    uint4* d = (uint4*)(A + (size_t)o * KDIM);
    d[i] = s[i];
    if (i < 64) d[512 + i] = s[512 + i];
}

// gemm: partial[kz][b][o] (bf16) = sum over k-window kz of B'*A'.
// B'-operand computed IN-KERNEL: prologue loads x-tile + de Boor -> vals
// regs; each step ds_writes the 16KB c-slice. A'-operand: gld16 ring-2.
// 8 waves (4x2 of 32x64, acc 2x4), counted vmcnt, 2 barriers/step, NT=9
// fully unrolled (static vals indices).
__global__ __launch_bounds__(512, 2) void gemm_kan(const ushort_t* __restrict__ A,
                                                   const float* __restrict__ x,
                                                   const float* __restrict__ g,
                                                   const float* __restrict__ bound_p,
                                                   ushort_t* __restrict__ partial) {
    __shared__ ushort_t ring[2 * BUF_ELEMS];   // 64 KiB: 2 x {X[128][64], Y[128][64]}
    int tid = threadIdx.x;
    int lane = tid & 63;
    int w = tid >> 6;             // 0..7
    int bid = blockIdx.x;
    // bid = bt*32 + ot*8 + kz: blocks sharing the A'-panel (same ot,kz) and
    // blocks sharing the x-slab (same bt,kz) both differ by multiples of 8
    // -> same XCD -> L2-shared.
    int bt = bid >> 5;            // 0..31
    int ot = (bid >> 3) & 3;      // 0..3
    int kz = bid & 7;             // 0..7 (= iblk)
    int brow0 = bt * TM;
    int ocol0 = ot * TN;

    int wr = w >> 1;              // 0..3 : M sub-tile (32 rows)
    int wc = w & 1;               // 0..1 : N sub-tile (64 cols)

    // ---------------- prologue: x-tile -> de Boor -> vals regs -------------
    // thread owns rows b = bgrp*8 + r (r=0..7), cols il = 2*il2, 2*il2+1.
    int il2 = tid & 31;
    int bgrp = tid >> 5;          // 0..15
    float bound = bound_p[0];
    float2 xv[8];
    const float* xbase = x + (size_t)(brow0 + bgrp * 8) * IN_DIM + kz * 64 + il2 * 2;
#pragma unroll
    for (int r = 0; r < 8; r++)
        xv[r] = *(const float2*)(xbase + (size_t)r * IN_DIM);

    unsigned int vals[8][9];      // packed bf16 pairs, all indices static
#pragma unroll
    for (int r = 0; r < 8; r++) {
        float fe[2][9];
#pragma unroll
        for (int e = 0; e < 2; e++) {
            float t = e ? xv[r].y : xv[r].x;
            t = fminf(fmaxf(t, -bound), bound);
            float u = (t + 8.0f) * 0.625f;     // knot spacing 1.6
            int j = (int)u;                     // g[j] <= t < g[j+1]
            j = min(max(j, 2), 7);
            float gj[6];
#pragma unroll
            for (int q = 0; q < 6; q++) gj[q] = g[j - 2 + q];
            const float invph[4] = {0.f, 0.625f, 0.3125f, 0.2083333333f};
            float Nv[4]; Nv[0] = 1.0f;
            float lv[4], rv[4];
#pragma unroll
            for (int p = 1; p <= 3; p++) {
                lv[p] = t - gj[3 - p];
                rv[p] = gj[2 + p] - t;
                float saved = 0.0f;
#pragma unroll
                for (int q = 0; q < p; q++) {
                    float temp = Nv[q] * invph[p];
                    Nv[q] = saved + rv[q + 1] * temp;
                    saved = lv[p - q] * temp;
                }
                Nv[p] = saved;
            }
            int c0 = j - 3;                     // c0==-1 at j==2: Nv[0] dropped
#pragma unroll
            for (int c = 0; c < 8; c++) {
                float v = 0.0f;
                v = (c == c0    ) ? Nv[0] : v;
                v = (c == c0 + 1) ? Nv[1] : v;
                v = (c == c0 + 2) ? Nv[2] : v;
                v = (c == c0 + 3) ? Nv[3] : v;
                fe[e][c] = v;
            }
            float sg = 1.0f / (1.0f + __expf(-t));
            fe[e][8] = t * sg;
        }
#pragma unroll
        for (int c = 0; c < 9; c++)
            vals[r][c] = (unsigned int)to_bf16(fe[0][c]) |
                         ((unsigned int)to_bf16(fe[1][c]) << 16);
    }

    // ---------------- accumulators ----------------
    f32x4 acc[2][4];
#pragma unroll
    for (int m = 0; m < 2; m++)
#pragma unroll
        for (int n = 0; n < 4; n++) acc[m][n] = (f32x4){0.f, 0.f, 0.f, 0.f};

    // A-staging: 16 x 1KB issues/step over 8 waves = 2/wave.
    int lr = lane >> 3;
    int lcb = (lane & 7) * 8;
    const ushort_t* asrc[2];
    int aoff[2];
#pragma unroll
    for (int i = 0; i < 2; i++) {
        int f = w * 2 + i;
        asrc[i] = A + (size_t)(ocol0 + f * 8 + lr) * KDIM + kz * KSLICE + lcb;
        aoff[i] = f * 1024;       // bytes within Y region
    }

#define STAGEA(T, B) do { char* yb_ = (char*)(ring + (B) * BUF_ELEMS + TM * BK); \
    _Pragma("unroll") for (int i_ = 0; i_ < 2; i_++)                             \
        gld16(asrc[i_] + (T) * BK, yb_ + aoff[i_]); } while (0)

#define DSWB(C, B) do { ushort_t* Xs_ = ring + (B) * BUF_ELEMS;                  \
    _Pragma("unroll") for (int r_ = 0; r_ < 8; r_++) {                           \
        int b_ = bgrp * 8 + r_;                                                  \
        int col_ = (il2 * 2) ^ ((b_ & 7) << 3);                                  \
        *(unsigned int*)&Xs_[b_ * BK + col_] = vals[r_][C]; } } while (0)

#define COMPUTE(B) do {                                                          \
    const ushort_t* Xs_ = ring + (B) * BUF_ELEMS;                                \
    const ushort_t* Ys_ = Xs_ + TM * BK;                                         \
    int xrow_ = wr * 32 + (lane & 15);                                           \
    int yrow_ = wc * 64 + (lane & 15);                                           \
    int swz_ = (lane & 7) << 3;                                                  \
    _Pragma("unroll") for (int kk_ = 0; kk_ < 2; kk_++) {                        \
        int kofs_ = (kk_ * 32 + ((lane >> 4) << 3)) ^ swz_;                      \
        short8 xf[2], yf[4];                                                     \
        _Pragma("unroll") for (int m_ = 0; m_ < 2; m_++)                         \
            xf[m_] = *(const short8*)&Xs_[(xrow_ + m_ * 16) * BK + kofs_];       \
        _Pragma("unroll") for (int n_ = 0; n_ < 4; n_++)                         \
            yf[n_] = *(const short8*)&Ys_[(yrow_ + n_ * 16) * BK + kofs_];       \
        _Pragma("unroll") for (int m_ = 0; m_ < 2; m_++)                         \
            _Pragma("unroll") for (int n_ = 0; n_ < 4; n_++)                     \
                acc[m_][n_] = __builtin_amdgcn_mfma_f32_16x16x32_bf16(           \
                    xf[m_], yf[n_], acc[m_][n_], 0, 0, 0);                       \
    } } while (0)

#define WAITVM(N) asm volatile("s_waitcnt vmcnt(" #N ")" ::: "memory")
#define WAITLGKM() asm volatile("s_waitcnt lgkmcnt(0)" ::: "memory")
#define BARRIER() do { __builtin_amdgcn_sched_barrier(0);                        \
    __builtin_amdgcn_s_barrier();                                                \
    __builtin_amdgcn_sched_barrier(0); } while (0)

    __builtin_amdgcn_sched_barrier(0);
    STAGEA(0, 0); STAGEA(1, 1);
    DSWB(0, 0);
    // step t: c = t. {wait A(t); B(t) writes done; barrier; compute;
    //                 barrier; stage A(t+2); ds-write B(t+1)}
#pragma unroll
    for (int t = 0; t < NT; ++t) {
        if (t < 8) { WAITVM(2); } else { WAITVM(0); }
        WAITLGKM();
        BARRIER();
        COMPUTE(t & 1);
        BARRIER();
        if (t < 7) STAGEA(t + 2, t & 1);
        if (t < 8) DSWB(t + 1, (t + 1) & 1);
    }

    // epilogue: bf16 partial stores. C/D layout col=lane&15, row=(lane>>4)*4+reg.
    ushort_t* pout = partial + (size_t)kz * OUT_ELEMS;
    int rgrp = (lane >> 4) * 4;
    int cidx = lane & 15;
#pragma unroll
    for (int m = 0; m < 2; m++) {
#pragma unroll
        for (int n = 0; n < 4; n++) {
            int o_idx = ocol0 + wc * 64 + n * 16 + cidx;
            int b_base = brow0 + wr * 32 + m * 16 + rgrp;
#pragma unroll
            for (int r = 0; r < 4; r++)
                pout[(size_t)(b_base + r) * OUT_DIM + o_idx] = to_bf16(acc[m][n][r]);
        }
    }
#undef STAGEA
#undef DSWB
#undef COMPUTE
#undef WAITVM
#undef WAITLGKM
#undef BARRIER
}

// out = sum of 8 bf16 partial slices, f32 result. 8 elems/thread.
__global__ __launch_bounds__(256) void reduce_k(const ushort_t* __restrict__ p,
                                                float* __restrict__ out) {
    size_t i8 = (size_t)blockIdx.x * 256 + threadIdx.x;   // index of 8-elem group
    float s[8] = {0, 0, 0, 0, 0, 0, 0, 0};
#pragma unroll
    for (int sl = 0; sl < SPLITK; sl++) {
        short8 v = ((const short8*)(p + (size_t)sl * OUT_ELEMS))[i8];
#pragma unroll
        for (int e = 0; e < 8; e++) s[e] += bf16_to_f((ushort_t)v[e]);
    }
    f32x4* o4 = (f32x4*)(out + i8 * 8);
    o4[0] = (f32x4){s[0], s[1], s[2], s[3]};
    o4[1] = (f32x4){s[4], s[5], s[6], s[7]};
}

extern "C" void kernel_launch(void* const* d_in, const int* in_sizes, int n_in,
                              void* d_out, int out_size, void* d_ws, size_t ws_size,
                              hipStream_t stream) {
    const float* x     = (const float*)d_in[0];
    const float* w_b   = (const float*)d_in[1];
    const float* w_s   = (const float*)d_in[2];
    const float* ctrl  = (const float*)d_in[3];
    const float* g     = (const float*)d_in[4];
    const float* bound = (const float*)d_in[5];
    float* out = (float*)d_out;

    ushort_t* Abuf    = (ushort_t*)d_ws;                               // 4.72 MB @ 0
    ushort_t* partial = (ushort_t*)((char*)d_ws + (size_t)(8u << 20)); // 8*2M*2 = 33.5 MB @ 8 MB

    prep_A<<<OUT_DIM, 512, 0, stream>>>(w_b, w_s, ctrl, Abuf);
    gemm_kan<<<(BATCH / TM) * (OUT_DIM / TN) * SPLITK, 512, 0, stream>>>(Abuf, x, g, bound, partial);
    reduce_k<<<OUT_ELEMS / 8 / 256, 256, 0, stream>>>(partial, out);
}

// Round 10
// 59.705 us; speedup vs baseline: 1.3376x; 1.3376x over previous
//
#include <hip/hip_runtime.h>
#include <hip/hip_bf16.h>

#define IN_DIM 512
#define OUT_DIM 512
#define BATCH 4096
#define NC 9                  // 8 active spline basis slots + 1 silu slot
#define KDIM (IN_DIM * NC)    // 4608
#define NCTRL 17
#define TM 256                // batch rows per block
#define TN 256                // out cols per block
#define BK 64
#define SPLITK 8
#define KSLICE (KDIM / SPLITK)   // 576
#define NT (KSLICE / BK)         // 9 K-steps per block
// ring-2: 2 x (TM+TN)*BK bf16 = 2 x 65536 B = 128 KiB LDS (dynamic)
#define BUF_ELEMS ((TM + TN) * BK)   // 32768
#define BUF_BYTES (BUF_ELEMS * 2)    // 65536
#define OUT_ELEMS ((size_t)BATCH * OUT_DIM)   // 2M

typedef unsigned short ushort_t;
typedef __attribute__((ext_vector_type(8))) short short8;
typedef __attribute__((ext_vector_type(4))) float f32x4;

__device__ inline ushort_t to_bf16(float f) {
    union { float f; unsigned int i; } v; v.f = f;
    unsigned int r = v.i + 0x7FFF + ((v.i >> 16) & 1);   // round-to-nearest-even
    return (ushort_t)(r >> 16);
}

__device__ inline float bf16_to_f(ushort_t u) {
    union { unsigned int i; float f; } v; v.i = ((unsigned int)u) << 16;
    return v.f;
}

__device__ inline void gld16(const ushort_t* g, void* l) {
    __builtin_amdgcn_global_load_lds(
        (const __attribute__((address_space(1))) void*)g,
        (__attribute__((address_space(3))) void*)l, 16, 0, 0);
}

// Pre-swizzled storage: element (row R, col k) lives at col k ^ ((R&7)<<3).
// XOR permutes 16B chunks inside each 128B segment: linear global_load_lds
// staging of 64-col tiles is unaffected; ds_read applies the same XOR.
// Verified conflict-free (SQ_LDS_BANK_CONFLICT == 0 in R2..R8).

// Fused prep: blocks [0,BATCH) build B' rows, blocks [BATCH,BATCH+OUT_DIM)
// build A' rows. Stage swizzled row in LDS -> coalesced 16B stores.
__global__ __launch_bounds__(512) void prep_AB(const float* __restrict__ x,
                                               const float* __restrict__ g,
                                               const float* __restrict__ bound_p,
                                               const float* __restrict__ w_b,
                                               const float* __restrict__ w_s,
                                               const float* __restrict__ ctrl,
                                               ushort_t* __restrict__ Bt,
                                               ushort_t* __restrict__ A) {
    __shared__ ushort_t rowbuf[KDIM];
    int blk = blockIdx.x;
    int i = threadIdx.x;
    ushort_t* dstrow;
    if (blk < BATCH) {
        int b = blk;
        float bound = bound_p[0];
        float t = x[(size_t)b * IN_DIM + i];
        t = fminf(fmaxf(t, -bound), bound);
        float u = (t + 8.0f) * 0.625f;       // knot spacing 1.6
        int j = (int)u;                       // g[j] <= t < g[j+1], j in [2,7]
        j = min(max(j, 2), 7);
        float gj[6];
#pragma unroll
        for (int r = 0; r < 6; r++) gj[r] = g[j - 2 + r];
        // de Boor; uniform knots -> denominators are p*1.6 (constants)
        const float invph[4] = {0.f, 0.625f, 0.3125f, 0.2083333333f};
        float Nv[4]; Nv[0] = 1.0f;
        float lv[4], rv[4];
#pragma unroll
        for (int p = 1; p <= 3; p++) {
            lv[p] = t - gj[3 - p];
            rv[p] = gj[2 + p] - t;
            float saved = 0.0f;
#pragma unroll
            for (int r = 0; r < p; r++) {
                float temp = Nv[r] * invph[p];
                Nv[r] = saved + rv[r + 1] * temp;
                saved = lv[p - r] * temp;
            }
            Nv[p] = saved;
        }
        int c0 = j - 3;                       // c0==-1 at j==2: Nv[0] (B_{-1}) dropped
        int swz = (b & 7) << 3;
        int k0 = i * NC;
#pragma unroll
        for (int c = 0; c < 8; c++) {
            float v = 0.0f;
            v = (c == c0    ) ? Nv[0] : v;
            v = (c == c0 + 1) ? Nv[1] : v;
            v = (c == c0 + 2) ? Nv[2] : v;
            v = (c == c0 + 3) ? Nv[3] : v;
            rowbuf[(k0 + c) ^ swz] = to_bf16(v);
        }
        float sg = 1.0f / (1.0f + __expf(-t));
        rowbuf[(k0 + 8) ^ swz] = to_bf16(t * sg);
        dstrow = Bt + (size_t)b * KDIM;
    } else {
        int o = blk - BATCH;
        float ws = w_s[(size_t)i * OUT_DIM + o];
        float wb = w_b[(size_t)i * OUT_DIM + o];
        const float* cp = ctrl + ((size_t)i * OUT_DIM + o) * NCTRL;
        int swz = (o & 7) << 3;
        int k0 = i * NC;
#pragma unroll
        for (int c = 0; c < 8; c++) rowbuf[(k0 + c) ^ swz] = to_bf16(ws * cp[c]);
        rowbuf[(k0 + 8) ^ swz] = to_bf16(wb);
        dstrow = A + (size_t)o * KDIM;
    }
    __syncthreads();
    const uint4* s = (const uint4*)rowbuf;               // 576 x 16B chunks
    uint4* d = (uint4*)dstrow;
    d[i] = s[i];
    if (i < 64) d[512 + i] = s[512 + i];
}

// partial[kz][b][o] (bf16) = sum_{k in slice kz} B'[b][k] * A'[o][k].
// TM=TN=256, 8 waves (2x4 of 128x64, acc 8x4), BK=64, ring-2 LDS
// (128 KB dynamic -> 1 block/CU, 2 waves/SIMD), counted vmcnt (never 0
// in main loop), 2 barriers/step. Plain bf16 stores, no atomics.
// Staged bytes: 256 blocks x 9 x 64 KB = 151 MB (vs R7's 302 MB).
__global__ __launch_bounds__(512, 2) void gemm_kan(const ushort_t* __restrict__ A,
                                                   const ushort_t* __restrict__ Bt,
                                                   ushort_t* __restrict__ partial) {
    extern __shared__ ushort_t ring[];   // 2 * BUF_ELEMS = 128 KiB
    int tid = threadIdx.x;
    int lane = tid & 63;
    int w = tid >> 6;             // 0..7
    int bid = blockIdx.x;
    // bid = bt*16 + ot*8 + kz: all blocks sharing the (ot,kz) A'-panel
    // (16 bt's) and the (bt,kz) B'-panel (2 ot's) have equal bid mod 8
    // -> same XCD under round-robin -> panels L2-resident per XCD.
    int bt = bid >> 4;            // 0..15
    int ot = (bid >> 3) & 1;      // 0..1
    int kz = bid & 7;             // 0..7
    int brow0 = bt * TM;
    int ocol0 = ot * TN;
    int k0 = kz * KSLICE;

    int wr = w >> 2;              // 0..1 : M sub-tile (128 rows of 256)
    int wc = w & 3;               // 0..3 : N sub-tile (64 cols of 256)

    f32x4 acc[8][4];
#pragma unroll
    for (int m = 0; m < 8; m++)
#pragma unroll
        for (int n = 0; n < 4; n++) acc[m][n] = (f32x4){0.f, 0.f, 0.f, 0.f};

    // staging: 64 x 1KB issues/step (32 for Xs=B' 256 rows, 32 for Ys=A'
    // 256 rows); wave w owns f = 8w..8w+7. LDS dst linear: f*1024.
    int lr = lane >> 3;           // row within 8-row group
    int lcb = (lane & 7) * 8;     // 16B chunk within 64-col row
    const ushort_t* src[8];
    int ldsoff[8];
#pragma unroll
    for (int i = 0; i < 8; i++) {
        int f = w * 8 + i;
        const ushort_t* basep = (f < 32)
            ? Bt + (size_t)(brow0 + f * 8 + lr) * KDIM
            : A  + (size_t)(ocol0 + (f - 32) * 8 + lr) * KDIM;
        src[i] = basep + k0 + lcb;
        ldsoff[i] = f * 1024;
    }
    char* ringb = (char*)ring;

// stages the NEXT tile (pointers auto-advance); each tile = 8 issues/wave
#define STAGE(B) do { char* bb_ = ringb + (B) * BUF_BYTES;                     \
    _Pragma("unroll") for (int i_ = 0; i_ < 8; i_++) {                         \
        gld16(src[i_], bb_ + ldsoff[i_]); src[i_] += BK; } } while (0)

#define COMPUTE(B) do {                                                        \
    const ushort_t* Xs_ = ring + (B) * BUF_ELEMS;                              \
    const ushort_t* Ys_ = Xs_ + TM * BK;                                       \
    int xrow_ = wr * 128 + (lane & 15);                                        \
    int yrow_ = wc * 64 + (lane & 15);                                         \
    int swz_ = (lane & 7) << 3;                                                \
    _Pragma("unroll") for (int kk_ = 0; kk_ < 2; kk_++) {                      \
        int kofs_ = (kk_ * 32 + ((lane >> 4) << 3)) ^ swz_;                    \
        short8 xf[8], yf[4];                                                   \
        _Pragma("unroll") for (int m_ = 0; m_ < 8; m_++)                       \
            xf[m_] = *(const short8*)&Xs_[(xrow_ + m_ * 16) * BK + kofs_];     \
        _Pragma("unroll") for (int n_ = 0; n_ < 4; n_++)                       \
            yf[n_] = *(const short8*)&Ys_[(yrow_ + n_ * 16) * BK + kofs_];     \
        _Pragma("unroll") for (int m_ = 0; m_ < 8; m_++)                       \
            _Pragma("unroll") for (int n_ = 0; n_ < 4; n_++)                   \
                acc[m_][n_] = __builtin_amdgcn_mfma_f32_16x16x32_bf16(         \
                    xf[m_], yf[n_], acc[m_][n_], 0, 0, 0);                     \
    } } while (0)

#define WAITVM(N) asm volatile("s_waitcnt vmcnt(" #N ")" ::: "memory")
#define BARRIER() do { __builtin_amdgcn_sched_barrier(0);                      \
    __builtin_amdgcn_s_barrier();                                              \
    __builtin_amdgcn_sched_barrier(0); } while (0)

    // prologue: 2 tiles in flight (16 gld16/wave outstanding)
    STAGE(0); STAGE(1);
    // steady: wait tile t (leave 8 = tile t+1 in flight), barrier (tile t
    // now fully in LDS across all waves), compute t, barrier (all waves
    // done reading buf t&1), stage tile t+2 into buf t&1.
    for (int t = 0; t < NT - 1; ++t) {
        WAITVM(8);
        BARRIER();
        COMPUTE(t & 1);
        BARRIER();
        if (t < NT - 2) STAGE(t & 1);
    }
    WAITVM(0); BARRIER(); COMPUTE((NT - 1) & 1);   // tile NT-1

    // epilogue: bf16 partial stores. C/D layout col=lane&15, row=(lane>>4)*4+reg.
    ushort_t* pout = partial + (size_t)kz * OUT_ELEMS;
    int rgrp = (lane >> 4) * 4;
    int cidx = lane & 15;
#pragma unroll
    for (int m = 0; m < 8; m++) {
#pragma unroll
        for (int n = 0; n < 4; n++) {
            int o_idx = ocol0 + wc * 64 + n * 16 + cidx;
            int b_base = brow0 + wr * 128 + m * 16 + rgrp;
#pragma unroll
            for (int r = 0; r < 4; r++)
                pout[(size_t)(b_base + r) * OUT_DIM + o_idx] = to_bf16(acc[m][n][r]);
        }
    }
#undef STAGE
#undef COMPUTE
#undef WAITVM
#undef BARRIER
}

// out = sum of 8 bf16 partial slices, f32 result. 8 elems/thread.
__global__ __launch_bounds__(256) void reduce_k(const ushort_t* __restrict__ p,
                                                float* __restrict__ out) {
    size_t i8 = (size_t)blockIdx.x * 256 + threadIdx.x;   // index of 8-elem group
    float s[8] = {0, 0, 0, 0, 0, 0, 0, 0};
#pragma unroll
    for (int sl = 0; sl < SPLITK; sl++) {
        short8 v = ((const short8*)(p + (size_t)sl * OUT_ELEMS))[i8];
#pragma unroll
        for (int e = 0; e < 8; e++) s[e] += bf16_to_f((ushort_t)v[e]);
    }
    f32x4* o4 = (f32x4*)(out + i8 * 8);
    o4[0] = (f32x4){s[0], s[1], s[2], s[3]};
    o4[1] = (f32x4){s[4], s[5], s[6], s[7]};
}

extern "C" void kernel_launch(void* const* d_in, const int* in_sizes, int n_in,
                              void* d_out, int out_size, void* d_ws, size_t ws_size,
                              hipStream_t stream) {
    const float* x     = (const float*)d_in[0];
    const float* w_b   = (const float*)d_in[1];
    const float* w_s   = (const float*)d_in[2];
    const float* ctrl  = (const float*)d_in[3];
    const float* g     = (const float*)d_in[4];
    const float* bound = (const float*)d_in[5];
    float* out = (float*)d_out;

    ushort_t* Abuf    = (ushort_t*)d_ws;                                // 4.72 MB @ 0
    ushort_t* Bbuf    = (ushort_t*)((char*)d_ws + (size_t)(8u << 20));  // 37.75 MB @ 8 MB
    ushort_t* partial = (ushort_t*)((char*)d_ws + (size_t)(48u << 20)); // 8*2M*2 = 33.5 MB @ 48 MB

    hipFuncSetAttribute((const void*)gemm_kan,
                        hipFuncAttributeMaxDynamicSharedMemorySize,
                        2 * BUF_BYTES);

    prep_AB<<<BATCH + OUT_DIM, 512, 0, stream>>>(x, g, bound, w_b, w_s, ctrl,
                                                 Bbuf, Abuf);
    gemm_kan<<<(BATCH / TM) * (OUT_DIM / TN) * SPLITK, 512, 2 * BUF_BYTES, stream>>>(Abuf, Bbuf, partial);
    reduce_k<<<OUT_ELEMS / 8 / 256, 256, 0, stream>>>(partial, out);
}